// Round 17
// baseline (607.676 us; speedup 1.0000x reference)
//
#include <hip/hip_runtime.h>
#include <hip/hip_fp16.h>
#include <cstdint>

#define NNODES 200000
#define NCH 128
#define NBATCH 4
#define DHW 262144      // 64*64*64
#define K1 192

// ---- workspace layout (bytes) ----
#define VOLH_OFF  0ull
#define VOLH_BYTES 134217728ull                  // 4*DHW*32 pairs *4B (fp16x2)
#define PART_OFF  134217728ull                   // 16384 blocks * 128 f32 = 8MB
#define STAT_OFF  142606336ull                   // 2KB
#define NWF_OFF   142608384ull                   // 24576 u32 = 96KB (node MLP A-frags)
#define WF_OFF    142706688ull                   // 6144 u32 = 24KB (voxel A-frags)
#define GT_OFF    257931264ull                   // 134MB gridT (fp16 pairs)
#define GRH_OFF   392149056ull                   // 134MB grh (fp16)

typedef _Float16 h2 __attribute__((ext_vector_type(2)));
typedef __fp16  fp16x2 __attribute__((ext_vector_type(2)));
typedef _Float16 f16x8 __attribute__((ext_vector_type(8)));
typedef float f32x4 __attribute__((ext_vector_type(4)));

__device__ __forceinline__ uint32_t pack_h2(float a, float b){
  fp16x2 p = __builtin_amdgcn_cvt_pkrtz(a, b);
  return __builtin_bit_cast(uint32_t, p);
}
__device__ __forceinline__ h2 as_h2(uint32_t w){ return __builtin_bit_cast(h2, w); }
__device__ __forceinline__ float siluf(float a){ return a / (1.f + __expf(-a)); }
__device__ __forceinline__ f32x4 mfma16(uint4 a, uint4 b, f32x4 c){
  return __builtin_amdgcn_mfma_f32_16x16x32_f16(
      __builtin_bit_cast(f16x8, a), __builtin_bit_cast(f16x8, b), c, 0, 0, 0);
}
__device__ __forceinline__ void atomic_pk_add_f16(uint32_t* addr, uint32_t val){
  asm volatile("global_atomic_pk_add_f16 %0, %1, off"
               :: "v"(addr), "v"(val) : "memory");
}

// ---------------- pack all MLP weights into MFMA A-fragments (one launch) ----------------
// A-frag: lane holds A[o = tt*16 + (lane&15)][k = s*32 + (lane>>4)*8 + 2q (+1)]
__global__ void pack_all(const float* __restrict__ w1, const float* __restrict__ w2,
                         const float* __restrict__ wn2g,
                         const float* __restrict__ wc1, const float* __restrict__ wc2,
                         uint32_t* __restrict__ nwf, uint32_t* __restrict__ wf)
{
  int t = blockIdx.x * 256 + threadIdx.x;
  if (t < 24576) {
    int q = t & 3, lane = (t >> 2) & 63;
    int vl = lane & 15, g = lane >> 4;
    if (t < 12288) {
      int f = t >> 8, s = f % 6, tt = f / 6;
      int o = tt * 16 + vl, k = s * 32 + g * 8 + 2 * q;
      nwf[t] = pack_h2(w1[o * K1 + k], w1[o * K1 + k + 1]);
    } else if (t < 20480) {
      int f = (t - 12288) >> 8, s = f & 3, tt = f >> 2;
      int o = tt * 16 + vl, k = s * 32 + g * 8 + 2 * q;
      nwf[t] = pack_h2(w2[o * 128 + k], w2[o * 128 + k + 1]);
    } else {
      int f = (t - 20480) >> 8, s = f & 3, tt = f >> 2;
      int o = tt * 16 + vl, k = s * 32 + g * 8 + 2 * q;
      nwf[t] = pack_h2(wn2g[o * 128 + k], wn2g[o * 128 + k + 1]);
    }
  } else if (t < 30720) {
    int u = t - 24576;
    if (u < 4096) {
      int q = u & 3, lane = (u >> 2) & 63, f = u >> 8;
      int s = f & 3, tt = f >> 2;
      int o = tt * 16 + (lane & 15);
      int k = s * 32 + (lane >> 4) * 8 + 2 * q;
      wf[u] = pack_h2(wc1[o * 128 + k], wc1[o * 128 + k + 1]);
    } else {
      int uu = u - 4096;
      int q = uu & 3, lane = (uu >> 2) & 63, f = uu >> 8;
      int s = f & 1, tt = f >> 1;
      int o = tt * 16 + (lane & 15);
      int k = s * 32 + (lane >> 4) * 8 + 2 * q;
      wf[u] = pack_h2(wc2[o * 64 + k], wc2[o * 64 + k + 1]);
    }
  }
}

// ---------------- transpose grid -> channel-last fp16 pairs (+ zero volh) ----------------
__global__ void transpose_kernel(const float* __restrict__ grid, uint32_t* __restrict__ gt,
                                 uint4* __restrict__ volz)
{
  __shared__ float tile[64][65];
  // fused volh zeroing: 512 uint4 per block
  {
    size_t base = (size_t)blockIdx.x * 512 + threadIdx.x;
    const uint4 z = make_uint4(0u, 0u, 0u, 0u);
    volz[base] = z;
    volz[base + 256] = z;
  }
  int bx = blockIdx.x;                  // 0..16383
  int b = bx >> 12;
  int dhw0 = (bx & 4095) << 6;
  const float* gbase = grid + ((size_t)b * 64) * DHW + dhw0;
  int c0 = threadIdx.x >> 6, d = threadIdx.x & 63;
  #pragma unroll
  for (int i = 0; i < 16; ++i)
    tile[i * 4 + c0][d] = gbase[(size_t)(i * 4 + c0) * DHW + d];
  __syncthreads();
  uint32_t* tb = gt + ((size_t)b * DHW + dhw0) * 32;
  int p = threadIdx.x & 31, r0 = threadIdx.x >> 5;
  #pragma unroll
  for (int i = 0; i < 8; ++i) {
    int dd = i * 8 + r0;
    tb[(size_t)dd * 32 + p] = pack_h2(tile[2 * p][dd], tile[2 * p + 1][dd]);
  }
}

// ---------------- fused node kernel: gather + MLP + LN + proj + scatter ----------------
// 64 nodes/block, 8 waves (512 thr). Wave w owns out-channels 16w..16w+15.
__launch_bounds__(512, 6)
__global__ void node_fused(const float* __restrict__ h, const float* __restrict__ x,
                           const uint32_t* __restrict__ gridT, const int* __restrict__ nbat,
                           const float* __restrict__ cmin, const float* __restrict__ sstr,
                           const uint32_t* __restrict__ nwf,
                           const float* __restrict__ b1, const float* __restrict__ b2,
                           const float* __restrict__ ln_g, const float* __restrict__ ln_b,
                           const float* __restrict__ bn2g,
                           float* __restrict__ hn_out, uint32_t* __restrict__ volh)
{
  __shared__ __align__(16) uint32_t zt[64][100];   // 25.6KB: z pairs; pz after proj
  __shared__ __align__(16) uint32_t g1z[64][68];   // 17.4KB
  __shared__ float wpart[8][64][2];                // 4KB
  __shared__ float cwS[64][8];                     // 2KB
  __shared__ int   cfS[64][8];                     // 2KB

  const int tid = threadIdx.x;
  const int lane = tid & 63, w = tid >> 6;         // w: 0..7
  const int g = lane >> 4, vl = lane & 15;
  const int n0 = blockIdx.x * 64;

  // ---- weights + biases into registers (hoisted) ----
  const uint4* nf4 = (const uint4*)nwf;
  uint4 a1f[6], a2f[4], apf[4];
  #pragma unroll
  for (int s = 0; s < 6; ++s) a1f[s] = nf4[(w * 6 + s) * 64 + lane];
  #pragma unroll
  for (int s = 0; s < 4; ++s) a2f[s] = nf4[3072 + (w * 4 + s) * 64 + lane];
  #pragma unroll
  for (int s = 0; s < 4; ++s) apf[s] = nf4[5120 + ((w & 3) * 4 + s) * 64 + lane];

  const int cbase = w * 16 + g * 4;
  float4 b1r = *(const float4*)&b1[cbase];
  float4 b2r = *(const float4*)&b2[cbase];
  float4 lgr = *(const float4*)&ln_g[cbase];
  float4 lbr = *(const float4*)&ln_b[cbase];
  float4 bnr = *(const float4*)&bn2g[(w & 3) * 16 + g * 4];

  // ---- phase A: corner data (1 corner/thread) + h pack ----
  {
    const float c0 = cmin[0], c1 = cmin[1], c2 = cmin[2];
    const float st0 = sstr[0], st1 = sstr[1], st2 = sstr[2];
    int nd = tid & 63, k = tid >> 6;      // corner k of node nd
    int n = n0 + nd;
    float gx = (x[n * 3 + 0] - c0) / st0;
    float gy = (x[n * 3 + 1] - c1) / st1;
    float gz = (x[n * 3 + 2] - c2) / st2;
    float fx0 = floorf(gx), fy0 = floorf(gy), fz0 = floorf(gz);
    float fx = fminf(fmaxf(gx - fx0, 0.f), 1.f);
    float fy = fminf(fmaxf(gy - fy0, 0.f), 1.f);
    float fz = fminf(fmaxf(gz - fz0, 0.f), 1.f);
    int ix0 = (int)fx0, iy0 = (int)fy0, iz0 = (int)fz0;
    int b = nbat[n];
    int xi = (k & 1) ? ix0 + 1 : ix0;
    int yi = (k & 2) ? iy0 + 1 : iy0;
    int zi = (k & 4) ? iz0 + 1 : iz0;
    float wx = (k & 1) ? fx : 1.f - fx;
    float wy = (k & 2) ? fy : 1.f - fy;
    float wz = (k & 4) ? fz : 1.f - fz;
    bool valid = (xi >= 0) & (xi < 64) & (yi >= 0) & (yi < 64) & (zi >= 0) & (zi < 64);
    int xc = min(max(xi, 0), 63), yc = min(max(yi, 0), 63), zc = min(max(zi, 0), 63);
    cwS[nd][k] = valid ? wx * wy * wz : 0.f;
    cfS[nd][k] = b * DHW + ((zc << 12) | (yc << 6) | xc);
  }
  {
    int nd = tid >> 3, o = tid & 7;
    const float4* hp = (const float4*)&h[(size_t)(n0 + nd) * NCH + o * 16];
    #pragma unroll
    for (int u = 0; u < 4; ++u) {
      float4 f = hp[u];
      zt[nd][o * 8 + 2 * u]     = pack_h2(f.x, f.y);
      zt[nd][o * 8 + 2 * u + 1] = pack_h2(f.z, f.w);
    }
  }
  __syncthreads();

  // ---- phase A2: gather, 8 nodes per wave, batched loads (16 in flight) ----
  {
    const int p = lane & 31, kb = lane >> 5;
    #pragma unroll
    for (int ib = 0; ib < 2; ++ib) {
      uint32_t gvr[4][4];
      #pragma unroll
      for (int i = 0; i < 4; ++i) {
        int nd = w * 8 + ib * 4 + i;
        #pragma unroll
        for (int jj = 0; jj < 4; ++jj) {
          int k = 2 * jj + kb;
          gvr[i][jj] = gridT[(size_t)cfS[nd][k] * 32 + p];
        }
      }
      #pragma unroll
      for (int i = 0; i < 4; ++i) {
        int nd = w * 8 + ib * 4 + i;
        float slo = 0.f, shi = 0.f;
        #pragma unroll
        for (int jj = 0; jj < 4; ++jj) {
          int k = 2 * jj + kb;
          float cwk = cwS[nd][k];
          h2 gv = as_h2(gvr[i][jj]);
          slo = fmaf(cwk, (float)gv.x, slo);
          shi = fmaf(cwk, (float)gv.y, shi);
        }
        slo += __shfl_xor(slo, 32);
        shi += __shfl_xor(shi, 32);
        if (lane < 32) zt[nd][64 + p] = pack_h2(slo, shi);
      }
    }
  }
  __syncthreads();

  // ---- layer1: z(192) -> silu -> g1z ----
  #pragma unroll
  for (int nc = 0; nc < 4; ++nc) {
    uint4 bfr[6];
    #pragma unroll
    for (int s = 0; s < 6; ++s) bfr[s] = *(const uint4*)&zt[nc * 16 + vl][s * 16 + g * 4];
    f32x4 acc;
    acc[0] = b1r.x; acc[1] = b1r.y; acc[2] = b1r.z; acc[3] = b1r.w;
    #pragma unroll
    for (int s = 0; s < 6; ++s) acc = mfma16(a1f[s], bfr[s], acc);
    uint2 pr;
    pr.x = pack_h2(siluf(acc[0]), siluf(acc[1]));
    pr.y = pack_h2(siluf(acc[2]), siluf(acc[3]));
    *(uint2*)&g1z[nc * 16 + vl][w * 8 + g * 2] = pr;
  }
  __syncthreads();

  // ---- layer2 + residual + LN partials ----
  float hnv[4][4];
  #pragma unroll
  for (int nc = 0; nc < 4; ++nc) {
    uint4 bfr[4];
    #pragma unroll
    for (int s = 0; s < 4; ++s) bfr[s] = *(const uint4*)&g1z[nc * 16 + vl][s * 16 + g * 4];
    f32x4 acc;
    acc[0] = b2r.x; acc[1] = b2r.y; acc[2] = b2r.z; acc[3] = b2r.w;
    #pragma unroll
    for (int s = 0; s < 4; ++s) acc = mfma16(a2f[s], bfr[s], acc);
    uint2 hp = *(const uint2*)&zt[nc * 16 + vl][w * 8 + g * 2];
    h2 p0 = as_h2(hp.x), p1 = as_h2(hp.y);
    float v0 = acc[0] + (float)p0.x;
    float v1 = acc[1] + (float)p0.y;
    float v2 = acc[2] + (float)p1.x;
    float v3 = acc[3] + (float)p1.y;
    hnv[nc][0] = v0; hnv[nc][1] = v1; hnv[nc][2] = v2; hnv[nc][3] = v3;
    float s_ = v0 + v1 + v2 + v3;
    float q_ = v0 * v0 + v1 * v1 + v2 * v2 + v3 * v3;
    s_ += __shfl_xor(s_, 16); q_ += __shfl_xor(q_, 16);
    s_ += __shfl_xor(s_, 32); q_ += __shfl_xor(q_, 32);
    if (lane < 16) { wpart[w][nc * 16 + lane][0] = s_; wpart[w][nc * 16 + lane][1] = q_; }
  }
  __syncthreads();

  // ---- LN finalize + hn write + pz pack (overwrite g1z) ----
  #pragma unroll
  for (int nc = 0; nc < 4; ++nc) {
    int node = nc * 16 + vl;
    float ssum = 0.f, qsum = 0.f;
    #pragma unroll
    for (int ww = 0; ww < 8; ++ww) {
      float2 pp = *(const float2*)&wpart[ww][node][0];
      ssum += pp.x; qsum += pp.y;
    }
    float mu = ssum * (1.f / 128.f);
    float var = qsum * (1.f / 128.f) - mu * mu;
    float rstd = rsqrtf(var + 1e-5f);
    float y0 = (hnv[nc][0] - mu) * rstd * lgr.x + lbr.x;
    float y1 = (hnv[nc][1] - mu) * rstd * lgr.y + lbr.y;
    float y2 = (hnv[nc][2] - mu) * rstd * lgr.z + lbr.z;
    float y3 = (hnv[nc][3] - mu) * rstd * lgr.w + lbr.w;
    *(float4*)&hn_out[(size_t)(n0 + node) * NCH + cbase] = make_float4(y0, y1, y2, y3);
    uint2 pz;
    pz.x = pack_h2(y0, y1);
    pz.y = pack_h2(y2, y3);
    *(uint2*)&g1z[node][w * 8 + g * 2] = pz;
  }
  __syncthreads();

  // ---- proj: 128 -> 64. Wave w: output tile (w&3), node half (w>>2). ----
  #pragma unroll
  for (int ncq = 0; ncq < 2; ++ncq) {
    int nc = (w >> 2) * 2 + ncq;
    int node = nc * 16 + vl;
    uint4 bfr[4];
    #pragma unroll
    for (int s = 0; s < 4; ++s) bfr[s] = *(const uint4*)&g1z[node][s * 16 + g * 4];
    f32x4 acc;
    acc[0] = bnr.x; acc[1] = bnr.y; acc[2] = bnr.z; acc[3] = bnr.w;
    #pragma unroll
    for (int s = 0; s < 4; ++s) acc = mfma16(apf[s], bfr[s], acc);
    uint2 pr;
    pr.x = pack_h2(acc[0], acc[1]);
    pr.y = pack_h2(acc[2], acc[3]);
    *(uint2*)&zt[node][(w & 3) * 8 + g * 2] = pr;
  }
  __syncthreads();

  // ---- scatter: 8 nodes/wave, straight from LDS ----
  {
    const int half = lane >> 5, c = lane & 31;
    for (int i = 0; i < 8; ++i) {
      int node = w * 8 + i;
      uint32_t pz = zt[node][c];
      h2 p = as_h2(pz);
      #pragma unroll
      for (int kk = 0; kk < 4; ++kk) {
        int k = 2 * kk + half;
        float wv = cwS[node][k];
        if (wv != 0.f) {
          int gidx = cfS[node][k];
          uint32_t v = pack_h2(wv * (float)p.x, wv * (float)p.y);
          atomic_pk_add_f16(&volh[(size_t)gidx * 32 + c], v);
        }
      }
    }
  }
}

// ---------------- per-voxel MLP kernel (MFMA, reads fp16 gridT + volh) ----------------
__launch_bounds__(256, 3)
__global__ void voxel_kernel(const uint32_t* __restrict__ gridT, const uint32_t* __restrict__ volh,
                             const uint32_t* __restrict__ wf, const float* __restrict__ bc1,
                             const float* __restrict__ bc2,
                             _Float16* __restrict__ grh, float* __restrict__ partials)
{
  __shared__ __align__(16) uint32_t xt[64][68];
  __shared__ __align__(16) uint32_t g1b[4][16][36];
  __shared__ float part_s[4][128];

  const int tid = threadIdx.x;
  const int lane = tid & 63, wv = tid >> 6;
  const int g = lane >> 4, vl = lane & 15;
  const int b = blockIdx.x >> 12;
  const int dhw0 = (blockIdx.x & 4095) << 6;

  // stage grid half straight from gridT (already channel-pair-last fp16)
  {
    const uint32_t* gt = gridT + ((size_t)b * DHW + dhw0) * 32;
    #pragma unroll
    for (int it = 0; it < 2; ++it) {
      int u = it * 256 + tid;
      int v = u >> 3, p4 = u & 7;
      *(uint4*)&xt[v][4 * p4] = *(const uint4*)&gt[(size_t)v * 32 + 4 * p4];
    }
  }
  // stage vol half (fp16 pairs)
  {
    const uint32_t* vb = volh + ((size_t)b * DHW + dhw0) * 32;
    #pragma unroll
    for (int it = 0; it < 2; ++it) {
      int u = it * 256 + tid;
      int v = u >> 3, p4 = u & 7;
      *(uint4*)&xt[v][32 + 4 * p4] = *(const uint4*)&vb[(size_t)v * 32 + 4 * p4];
    }
  }

  const uint4* wf4 = (const uint4*)wf;
  uint4 w1f[4][4], w2f[4][2];
  #pragma unroll
  for (int t = 0; t < 4; ++t)
    #pragma unroll
    for (int s = 0; s < 4; ++s)
      w1f[t][s] = wf4[(t * 4 + s) * 64 + lane];
  #pragma unroll
  for (int t = 0; t < 4; ++t)
    #pragma unroll
    for (int s = 0; s < 2; ++s)
      w2f[t][s] = wf4[1024 + (t * 2 + s) * 64 + lane];

  f32x4 acc1[4];
  #pragma unroll
  for (int t = 0; t < 4; ++t) {
    #pragma unroll
    for (int r = 0; r < 4; ++r) acc1[t][r] = bc1[t * 16 + g * 4 + r];
  }

  __syncthreads();

  const int v = wv * 16 + vl;
  #pragma unroll
  for (int s = 0; s < 4; ++s) {
    uint4 xb = *(const uint4*)&xt[v][s * 16 + g * 4];
    #pragma unroll
    for (int t = 0; t < 4; ++t) acc1[t] = mfma16(w1f[t][s], xb, acc1[t]);
  }

  #pragma unroll
  for (int t = 0; t < 4; ++t) {
    uint2 pr;
    pr.x = pack_h2(siluf(acc1[t][0]), siluf(acc1[t][1]));
    pr.y = pack_h2(siluf(acc1[t][2]), siluf(acc1[t][3]));
    *(uint2*)&g1b[wv][vl][t * 8 + g * 2] = pr;
  }
  asm volatile("s_waitcnt lgkmcnt(0)" ::: "memory");

  f32x4 acc2[4];
  #pragma unroll
  for (int t = 0; t < 4; ++t) {
    #pragma unroll
    for (int r = 0; r < 4; ++r) acc2[t][r] = bc2[t * 16 + g * 4 + r];
  }
  #pragma unroll
  for (int s = 0; s < 2; ++s) {
    uint4 gv = *(const uint4*)&g1b[wv][vl][s * 16 + g * 4];
    #pragma unroll
    for (int t = 0; t < 4; ++t) acc2[t] = mfma16(w2f[t][s], gv, acc2[t]);
  }

  // residual from staged fp16 grid + store fp16 + per-block stats
  const int dhw = dhw0 + v;
  #pragma unroll
  for (int t = 0; t < 4; ++t) {
    uint2 gp = *(const uint2*)&xt[v][t * 8 + g * 2];
    h2 g0 = as_h2(gp.x), g1 = as_h2(gp.y);
    float gc[4] = {(float)g0.x, (float)g0.y, (float)g1.x, (float)g1.y};
    #pragma unroll
    for (int r = 0; r < 4; ++r) {
      int o = t * 16 + g * 4 + r;
      float grv = gc[r] + acc2[t][r];
      grh[(size_t)(b * 64 + o) * DHW + dhw] = (_Float16)grv;
      float sv = grv, qv = grv * grv;
      sv += __shfl_xor(sv, 1, 64); qv += __shfl_xor(qv, 1, 64);
      sv += __shfl_xor(sv, 2, 64); qv += __shfl_xor(qv, 2, 64);
      sv += __shfl_xor(sv, 4, 64); qv += __shfl_xor(qv, 4, 64);
      sv += __shfl_xor(sv, 8, 64); qv += __shfl_xor(qv, 8, 64);
      if (vl == 0) { part_s[wv][2 * o] = sv; part_s[wv][2 * o + 1] = qv; }
    }
  }
  __syncthreads();
  if (tid < 128)
    partials[(size_t)blockIdx.x * 128 + tid] =
        part_s[0][tid] + part_s[1][tid] + part_s[2][tid] + part_s[3][tid];
}

// ---------------- reduce partials -> per (b,c) scale/shift ----------------
__global__ void stats_kernel(const float* __restrict__ partials, const float* __restrict__ in_g,
                             const float* __restrict__ in_b, float* __restrict__ stats)
{
  int bo = blockIdx.x;
  int b = bo >> 6, o = bo & 63;
  float s = 0.f, q = 0.f;
  for (int k = threadIdx.x; k < 4096; k += 256) {
    const float* pp = partials + (size_t)(b * 4096 + k) * 128 + 2 * o;
    s += pp[0]; q += pp[1];
  }
  __shared__ float sred[256], qred[256];
  sred[threadIdx.x] = s; qred[threadIdx.x] = q;
  __syncthreads();
  for (int st = 128; st >= 1; st >>= 1) {
    if (threadIdx.x < st) { sred[threadIdx.x] += sred[threadIdx.x + st]; qred[threadIdx.x] += qred[threadIdx.x + st]; }
    __syncthreads();
  }
  if (threadIdx.x == 0) {
    float mu = sred[0] * (1.f / (float)DHW);
    float var = qred[0] * (1.f / (float)DHW) - mu * mu;
    float rstd = rsqrtf(var + 1e-5f);
    float scale = rstd * in_g[o];
    stats[2 * bo] = scale;
    stats[2 * bo + 1] = in_b[o] - mu * scale;
  }
}

// ---------------- apply instance norm: grh (fp16) -> gr_out (f32), vectorized ----------------
__global__ void norm_kernel(const uint2* __restrict__ grh2, const float* __restrict__ stats,
                            float* __restrict__ gr)
{
  const size_t total = (size_t)NBATCH * 64 * DHW / 4;   // uint2 count (4 fp16 each)
  size_t stride = (size_t)gridDim.x * 256;
  for (size_t i = blockIdx.x * 256 + threadIdx.x; i < total; i += stride) {
    int bo = (int)(i >> 16);                             // 65536 uint2 per (b,o)
    float scale = stats[2 * bo], shift = stats[2 * bo + 1];
    uint2 u = grh2[i];
    h2 p0 = as_h2(u.x), p1 = as_h2(u.y);
    float4 o;
    o.x = fmaf((float)p0.x, scale, shift);
    o.y = fmaf((float)p0.y, scale, shift);
    o.z = fmaf((float)p1.x, scale, shift);
    o.w = fmaf((float)p1.y, scale, shift);
    *(float4*)&gr[4 * i] = o;
  }
}

extern "C" void kernel_launch(void* const* d_in, const int* in_sizes, int n_in,
                              void* d_out, int out_size, void* d_ws, size_t ws_size,
                              hipStream_t stream)
{
  const float* h     = (const float*)d_in[0];
  const float* x     = (const float*)d_in[1];
  const float* grid  = (const float*)d_in[2];
  const int*   nbat  = (const int*)d_in[3];
  const float* cmin  = (const float*)d_in[4];
  const float* sstr  = (const float*)d_in[5];
  const float* w1    = (const float*)d_in[6];
  const float* b1    = (const float*)d_in[7];
  const float* w2    = (const float*)d_in[8];
  const float* b2    = (const float*)d_in[9];
  const float* ln_g  = (const float*)d_in[10];
  const float* ln_b  = (const float*)d_in[11];
  const float* wn2g  = (const float*)d_in[12];
  const float* bn2g  = (const float*)d_in[13];
  const float* wc1   = (const float*)d_in[14];
  const float* bc1   = (const float*)d_in[15];
  const float* wc2   = (const float*)d_in[16];
  const float* bc2   = (const float*)d_in[17];
  const float* in_g  = (const float*)d_in[18];
  const float* in_b  = (const float*)d_in[19];

  float* hn_out = (float*)d_out;
  float* gr_out = (float*)d_out + (size_t)NNODES * NCH;

  char* ws = (char*)d_ws;
  uint32_t* volh     = (uint32_t*)(ws + VOLH_OFF);     // 134MB fp16 pairs
  float*    partials = (float*)(ws + PART_OFF);
  float*    stats    = (float*)(ws + STAT_OFF);
  uint32_t* nwf      = (uint32_t*)(ws + NWF_OFF);
  uint32_t* wf       = (uint32_t*)(ws + WF_OFF);
  uint32_t* gridT    = (uint32_t*)(ws + GT_OFF);       // 134MB
  _Float16* grh      = (_Float16*)(ws + GRH_OFF);      // 134MB

  pack_all<<<120, 256, 0, stream>>>(w1, w2, wn2g, wc1, wc2, nwf, wf);
  transpose_kernel<<<16384, 256, 0, stream>>>(grid, gridT, (uint4*)volh);
  node_fused<<<3125, 512, 0, stream>>>(h, x, gridT, nbat, cmin, sstr, nwf,
                                       b1, b2, ln_g, ln_b, bn2g, hn_out, volh);
  voxel_kernel<<<16384, 256, 0, stream>>>(gridT, volh, wf, bc1, bc2, grh, partials);
  stats_kernel<<<256, 256, 0, stream>>>(partials, in_g, in_b, stats);
  norm_kernel<<<8192, 256, 0, stream>>>((const uint2*)grh, stats, gr_out);
}

// Round 18
// 560.864 us; speedup vs baseline: 1.0835x; 1.0835x over previous
//
#include <hip/hip_runtime.h>
#include <hip/hip_fp16.h>
#include <cstdint>

#define NNODES 200000
#define NCH 128
#define NBATCH 4
#define DHW 262144      // 64*64*64
#define K1 192

// ---- workspace layout (bytes) ----
#define VOLH_OFF  0ull
#define VOLH_BYTES 134217728ull                  // 4*DHW*32 pairs *4B (fp16x2)
#define PART_OFF  134217728ull                   // 16384 blocks * 128 f32 = 8MB
#define STAT_OFF  142606336ull                   // 2KB
#define NWF_OFF   142608384ull                   // 24576 u32 = 96KB (node MLP A-frags)
#define WF_OFF    142706688ull                   // 6144 u32 = 24KB (voxel A-frags)
#define GT_OFF    257931264ull                   // 134MB gridT (fp16 pairs)
#define GRH_OFF   392149056ull                   // 134MB grh (fp16)

typedef _Float16 h2 __attribute__((ext_vector_type(2)));
typedef __fp16  fp16x2 __attribute__((ext_vector_type(2)));
typedef _Float16 f16x8 __attribute__((ext_vector_type(8)));
typedef float f32x4 __attribute__((ext_vector_type(4)));

__device__ __forceinline__ uint32_t pack_h2(float a, float b){
  fp16x2 p = __builtin_amdgcn_cvt_pkrtz(a, b);
  return __builtin_bit_cast(uint32_t, p);
}
__device__ __forceinline__ h2 as_h2(uint32_t w){ return __builtin_bit_cast(h2, w); }
__device__ __forceinline__ float siluf(float a){ return a / (1.f + __expf(-a)); }
__device__ __forceinline__ f32x4 mfma16(uint4 a, uint4 b, f32x4 c){
  return __builtin_amdgcn_mfma_f32_16x16x32_f16(
      __builtin_bit_cast(f16x8, a), __builtin_bit_cast(f16x8, b), c, 0, 0, 0);
}
__device__ __forceinline__ void atomic_pk_add_f16(uint32_t* addr, uint32_t val){
  asm volatile("global_atomic_pk_add_f16 %0, %1, off"
               :: "v"(addr), "v"(val) : "memory");
}

// ---------------- pack all MLP weights into MFMA A-fragments (one launch) ----------------
// A-frag: lane holds A[o = tt*16 + (lane&15)][k = s*32 + (lane>>4)*8 + 2q (+1)]
__global__ void pack_all(const float* __restrict__ w1, const float* __restrict__ w2,
                         const float* __restrict__ wn2g,
                         const float* __restrict__ wc1, const float* __restrict__ wc2,
                         uint32_t* __restrict__ nwf, uint32_t* __restrict__ wf)
{
  int t = blockIdx.x * 256 + threadIdx.x;
  if (t < 24576) {
    int q = t & 3, lane = (t >> 2) & 63;
    int vl = lane & 15, g = lane >> 4;
    if (t < 12288) {
      int f = t >> 8, s = f % 6, tt = f / 6;
      int o = tt * 16 + vl, k = s * 32 + g * 8 + 2 * q;
      nwf[t] = pack_h2(w1[o * K1 + k], w1[o * K1 + k + 1]);
    } else if (t < 20480) {
      int f = (t - 12288) >> 8, s = f & 3, tt = f >> 2;
      int o = tt * 16 + vl, k = s * 32 + g * 8 + 2 * q;
      nwf[t] = pack_h2(w2[o * 128 + k], w2[o * 128 + k + 1]);
    } else {
      int f = (t - 20480) >> 8, s = f & 3, tt = f >> 2;
      int o = tt * 16 + vl, k = s * 32 + g * 8 + 2 * q;
      nwf[t] = pack_h2(wn2g[o * 128 + k], wn2g[o * 128 + k + 1]);
    }
  } else if (t < 30720) {
    int u = t - 24576;
    if (u < 4096) {
      int q = u & 3, lane = (u >> 2) & 63, f = u >> 8;
      int s = f & 3, tt = f >> 2;
      int o = tt * 16 + (lane & 15);
      int k = s * 32 + (lane >> 4) * 8 + 2 * q;
      wf[u] = pack_h2(wc1[o * 128 + k], wc1[o * 128 + k + 1]);
    } else {
      int uu = u - 4096;
      int q = uu & 3, lane = (uu >> 2) & 63, f = uu >> 8;
      int s = f & 1, tt = f >> 1;
      int o = tt * 16 + (lane & 15);
      int k = s * 32 + (lane >> 4) * 8 + 2 * q;
      wf[u] = pack_h2(wc2[o * 64 + k], wc2[o * 64 + k + 1]);
    }
  }
}

// ---------------- transpose grid -> channel-last fp16 pairs (+ zero volh) ----------------
__global__ void transpose_kernel(const float* __restrict__ grid, uint32_t* __restrict__ gt,
                                 uint4* __restrict__ volz)
{
  __shared__ float tile[64][65];
  // fused volh zeroing: 512 uint4 per block
  {
    size_t base = (size_t)blockIdx.x * 512 + threadIdx.x;
    const uint4 z = make_uint4(0u, 0u, 0u, 0u);
    volz[base] = z;
    volz[base + 256] = z;
  }
  int bx = blockIdx.x;                  // 0..16383
  int b = bx >> 12;
  int dhw0 = (bx & 4095) << 6;
  const float* gbase = grid + ((size_t)b * 64) * DHW + dhw0;
  int c0 = threadIdx.x >> 6, d = threadIdx.x & 63;
  #pragma unroll
  for (int i = 0; i < 16; ++i)
    tile[i * 4 + c0][d] = gbase[(size_t)(i * 4 + c0) * DHW + d];
  __syncthreads();
  uint32_t* tb = gt + ((size_t)b * DHW + dhw0) * 32;
  int p = threadIdx.x & 31, r0 = threadIdx.x >> 5;
  #pragma unroll
  for (int i = 0; i < 8; ++i) {
    int dd = i * 8 + r0;
    tb[(size_t)dd * 32 + p] = pack_h2(tile[2 * p][dd], tile[2 * p + 1][dd]);
  }
}

// ---------------- fused node kernel: gather + MLP + LN + proj + scatter ----------------
// 64 nodes/block, 8 waves (512 thr). Wave w owns out-channels 16w..16w+15.
__launch_bounds__(512)
__global__ void node_fused(const float* __restrict__ h, const float* __restrict__ x,
                           const uint32_t* __restrict__ gridT, const int* __restrict__ nbat,
                           const float* __restrict__ cmin, const float* __restrict__ sstr,
                           const uint32_t* __restrict__ nwf,
                           const float* __restrict__ b1, const float* __restrict__ b2,
                           const float* __restrict__ ln_g, const float* __restrict__ ln_b,
                           const float* __restrict__ bn2g,
                           float* __restrict__ hn_out, uint32_t* __restrict__ volh)
{
  __shared__ __align__(16) uint32_t zt[64][100];   // 25.6KB: z pairs; pz after proj
  __shared__ __align__(16) uint32_t g1z[64][68];   // 17.4KB
  __shared__ float wpart[8][64][2];                // 4KB
  __shared__ float cwS[64][8];                     // 2KB
  __shared__ int   cfS[64][8];                     // 2KB

  const int tid = threadIdx.x;
  const int lane = tid & 63, w = tid >> 6;         // w: 0..7
  const int g = lane >> 4, vl = lane & 15;
  const int n0 = blockIdx.x * 64;

  // ---- weights + biases into registers (hoisted) ----
  const uint4* nf4 = (const uint4*)nwf;
  uint4 a1f[6], a2f[4], apf[4];
  #pragma unroll
  for (int s = 0; s < 6; ++s) a1f[s] = nf4[(w * 6 + s) * 64 + lane];
  #pragma unroll
  for (int s = 0; s < 4; ++s) a2f[s] = nf4[3072 + (w * 4 + s) * 64 + lane];
  #pragma unroll
  for (int s = 0; s < 4; ++s) apf[s] = nf4[5120 + ((w & 3) * 4 + s) * 64 + lane];

  const int cbase = w * 16 + g * 4;
  float4 b1r = *(const float4*)&b1[cbase];
  float4 b2r = *(const float4*)&b2[cbase];
  float4 lgr = *(const float4*)&ln_g[cbase];
  float4 lbr = *(const float4*)&ln_b[cbase];
  float4 bnr = *(const float4*)&bn2g[(w & 3) * 16 + g * 4];

  // ---- phase A: corner data (1 corner/thread) + h pack ----
  {
    const float c0 = cmin[0], c1 = cmin[1], c2 = cmin[2];
    const float st0 = sstr[0], st1 = sstr[1], st2 = sstr[2];
    int nd = tid & 63, k = tid >> 6;      // corner k of node nd
    int n = n0 + nd;
    float gx = (x[n * 3 + 0] - c0) / st0;
    float gy = (x[n * 3 + 1] - c1) / st1;
    float gz = (x[n * 3 + 2] - c2) / st2;
    float fx0 = floorf(gx), fy0 = floorf(gy), fz0 = floorf(gz);
    float fx = fminf(fmaxf(gx - fx0, 0.f), 1.f);
    float fy = fminf(fmaxf(gy - fy0, 0.f), 1.f);
    float fz = fminf(fmaxf(gz - fz0, 0.f), 1.f);
    int ix0 = (int)fx0, iy0 = (int)fy0, iz0 = (int)fz0;
    int b = nbat[n];
    int xi = (k & 1) ? ix0 + 1 : ix0;
    int yi = (k & 2) ? iy0 + 1 : iy0;
    int zi = (k & 4) ? iz0 + 1 : iz0;
    float wx = (k & 1) ? fx : 1.f - fx;
    float wy = (k & 2) ? fy : 1.f - fy;
    float wz = (k & 4) ? fz : 1.f - fz;
    bool valid = (xi >= 0) & (xi < 64) & (yi >= 0) & (yi < 64) & (zi >= 0) & (zi < 64);
    int xc = min(max(xi, 0), 63), yc = min(max(yi, 0), 63), zc = min(max(zi, 0), 63);
    cwS[nd][k] = valid ? wx * wy * wz : 0.f;
    cfS[nd][k] = b * DHW + ((zc << 12) | (yc << 6) | xc);
  }
  {
    int nd = tid >> 3, o = tid & 7;
    const float4* hp = (const float4*)&h[(size_t)(n0 + nd) * NCH + o * 16];
    #pragma unroll
    for (int u = 0; u < 4; ++u) {
      float4 f = hp[u];
      zt[nd][o * 8 + 2 * u]     = pack_h2(f.x, f.y);
      zt[nd][o * 8 + 2 * u + 1] = pack_h2(f.z, f.w);
    }
  }
  __syncthreads();

  // ---- phase A2: gather, 8 nodes per wave, batched loads (16 in flight) ----
  {
    const int p = lane & 31, kb = lane >> 5;
    #pragma unroll
    for (int ib = 0; ib < 2; ++ib) {
      uint32_t gvr[4][4];
      #pragma unroll
      for (int i = 0; i < 4; ++i) {
        int nd = w * 8 + ib * 4 + i;
        #pragma unroll
        for (int jj = 0; jj < 4; ++jj) {
          int k = 2 * jj + kb;
          gvr[i][jj] = gridT[(size_t)cfS[nd][k] * 32 + p];
        }
      }
      #pragma unroll
      for (int i = 0; i < 4; ++i) {
        int nd = w * 8 + ib * 4 + i;
        float slo = 0.f, shi = 0.f;
        #pragma unroll
        for (int jj = 0; jj < 4; ++jj) {
          int k = 2 * jj + kb;
          float cwk = cwS[nd][k];
          h2 gv = as_h2(gvr[i][jj]);
          slo = fmaf(cwk, (float)gv.x, slo);
          shi = fmaf(cwk, (float)gv.y, shi);
        }
        slo += __shfl_xor(slo, 32);
        shi += __shfl_xor(shi, 32);
        if (lane < 32) zt[nd][64 + p] = pack_h2(slo, shi);
      }
    }
  }
  __syncthreads();

  // ---- layer1: z(192) -> silu -> g1z ----
  #pragma unroll
  for (int nc = 0; nc < 4; ++nc) {
    uint4 bfr[6];
    #pragma unroll
    for (int s = 0; s < 6; ++s) bfr[s] = *(const uint4*)&zt[nc * 16 + vl][s * 16 + g * 4];
    f32x4 acc;
    acc[0] = b1r.x; acc[1] = b1r.y; acc[2] = b1r.z; acc[3] = b1r.w;
    #pragma unroll
    for (int s = 0; s < 6; ++s) acc = mfma16(a1f[s], bfr[s], acc);
    uint2 pr;
    pr.x = pack_h2(siluf(acc[0]), siluf(acc[1]));
    pr.y = pack_h2(siluf(acc[2]), siluf(acc[3]));
    *(uint2*)&g1z[nc * 16 + vl][w * 8 + g * 2] = pr;
  }
  __syncthreads();

  // ---- layer2 + residual + LN partials ----
  float hnv[4][4];
  #pragma unroll
  for (int nc = 0; nc < 4; ++nc) {
    uint4 bfr[4];
    #pragma unroll
    for (int s = 0; s < 4; ++s) bfr[s] = *(const uint4*)&g1z[nc * 16 + vl][s * 16 + g * 4];
    f32x4 acc;
    acc[0] = b2r.x; acc[1] = b2r.y; acc[2] = b2r.z; acc[3] = b2r.w;
    #pragma unroll
    for (int s = 0; s < 4; ++s) acc = mfma16(a2f[s], bfr[s], acc);
    uint2 hp = *(const uint2*)&zt[nc * 16 + vl][w * 8 + g * 2];
    h2 p0 = as_h2(hp.x), p1 = as_h2(hp.y);
    float v0 = acc[0] + (float)p0.x;
    float v1 = acc[1] + (float)p0.y;
    float v2 = acc[2] + (float)p1.x;
    float v3 = acc[3] + (float)p1.y;
    hnv[nc][0] = v0; hnv[nc][1] = v1; hnv[nc][2] = v2; hnv[nc][3] = v3;
    float s_ = v0 + v1 + v2 + v3;
    float q_ = v0 * v0 + v1 * v1 + v2 * v2 + v3 * v3;
    s_ += __shfl_xor(s_, 16); q_ += __shfl_xor(q_, 16);
    s_ += __shfl_xor(s_, 32); q_ += __shfl_xor(q_, 32);
    if (lane < 16) { wpart[w][nc * 16 + lane][0] = s_; wpart[w][nc * 16 + lane][1] = q_; }
  }
  __syncthreads();

  // ---- LN finalize + hn write + pz pack (overwrite g1z) ----
  #pragma unroll
  for (int nc = 0; nc < 4; ++nc) {
    int node = nc * 16 + vl;
    float ssum = 0.f, qsum = 0.f;
    #pragma unroll
    for (int ww = 0; ww < 8; ++ww) {
      float2 pp = *(const float2*)&wpart[ww][node][0];
      ssum += pp.x; qsum += pp.y;
    }
    float mu = ssum * (1.f / 128.f);
    float var = qsum * (1.f / 128.f) - mu * mu;
    float rstd = rsqrtf(var + 1e-5f);
    float y0 = (hnv[nc][0] - mu) * rstd * lgr.x + lbr.x;
    float y1 = (hnv[nc][1] - mu) * rstd * lgr.y + lbr.y;
    float y2 = (hnv[nc][2] - mu) * rstd * lgr.z + lbr.z;
    float y3 = (hnv[nc][3] - mu) * rstd * lgr.w + lbr.w;
    *(float4*)&hn_out[(size_t)(n0 + node) * NCH + cbase] = make_float4(y0, y1, y2, y3);
    uint2 pz;
    pz.x = pack_h2(y0, y1);
    pz.y = pack_h2(y2, y3);
    *(uint2*)&g1z[node][w * 8 + g * 2] = pz;
  }
  __syncthreads();

  // ---- proj: 128 -> 64. Wave w: output tile (w&3), node half (w>>2). ----
  #pragma unroll
  for (int ncq = 0; ncq < 2; ++ncq) {
    int nc = (w >> 2) * 2 + ncq;
    int node = nc * 16 + vl;
    uint4 bfr[4];
    #pragma unroll
    for (int s = 0; s < 4; ++s) bfr[s] = *(const uint4*)&g1z[node][s * 16 + g * 4];
    f32x4 acc;
    acc[0] = bnr.x; acc[1] = bnr.y; acc[2] = bnr.z; acc[3] = bnr.w;
    #pragma unroll
    for (int s = 0; s < 4; ++s) acc = mfma16(apf[s], bfr[s], acc);
    uint2 pr;
    pr.x = pack_h2(acc[0], acc[1]);
    pr.y = pack_h2(acc[2], acc[3]);
    *(uint2*)&zt[node][(w & 3) * 8 + g * 2] = pr;
  }
  __syncthreads();

  // ---- scatter: 8 nodes/wave, straight from LDS ----
  {
    const int half = lane >> 5, c = lane & 31;
    for (int i = 0; i < 8; ++i) {
      int node = w * 8 + i;
      uint32_t pz = zt[node][c];
      h2 p = as_h2(pz);
      #pragma unroll
      for (int kk = 0; kk < 4; ++kk) {
        int k = 2 * kk + half;
        float wv = cwS[node][k];
        if (wv != 0.f) {
          int gidx = cfS[node][k];
          uint32_t v = pack_h2(wv * (float)p.x, wv * (float)p.y);
          atomic_pk_add_f16(&volh[(size_t)gidx * 32 + c], v);
        }
      }
    }
  }
}

// ---------------- per-voxel MLP kernel (MFMA, reads fp16 gridT + volh) ----------------
__launch_bounds__(256, 3)
__global__ void voxel_kernel(const uint32_t* __restrict__ gridT, const uint32_t* __restrict__ volh,
                             const uint32_t* __restrict__ wf, const float* __restrict__ bc1,
                             const float* __restrict__ bc2,
                             _Float16* __restrict__ grh, float* __restrict__ partials)
{
  __shared__ __align__(16) uint32_t xt[64][68];
  __shared__ __align__(16) uint32_t g1b[4][16][36];
  __shared__ float part_s[4][128];

  const int tid = threadIdx.x;
  const int lane = tid & 63, wv = tid >> 6;
  const int g = lane >> 4, vl = lane & 15;
  const int b = blockIdx.x >> 12;
  const int dhw0 = (blockIdx.x & 4095) << 6;

  // stage grid half straight from gridT (already channel-pair-last fp16)
  {
    const uint32_t* gt = gridT + ((size_t)b * DHW + dhw0) * 32;
    #pragma unroll
    for (int it = 0; it < 2; ++it) {
      int u = it * 256 + tid;
      int v = u >> 3, p4 = u & 7;
      *(uint4*)&xt[v][4 * p4] = *(const uint4*)&gt[(size_t)v * 32 + 4 * p4];
    }
  }
  // stage vol half (fp16 pairs)
  {
    const uint32_t* vb = volh + ((size_t)b * DHW + dhw0) * 32;
    #pragma unroll
    for (int it = 0; it < 2; ++it) {
      int u = it * 256 + tid;
      int v = u >> 3, p4 = u & 7;
      *(uint4*)&xt[v][32 + 4 * p4] = *(const uint4*)&vb[(size_t)v * 32 + 4 * p4];
    }
  }

  const uint4* wf4 = (const uint4*)wf;
  uint4 w1f[4][4], w2f[4][2];
  #pragma unroll
  for (int t = 0; t < 4; ++t)
    #pragma unroll
    for (int s = 0; s < 4; ++s)
      w1f[t][s] = wf4[(t * 4 + s) * 64 + lane];
  #pragma unroll
  for (int t = 0; t < 4; ++t)
    #pragma unroll
    for (int s = 0; s < 2; ++s)
      w2f[t][s] = wf4[1024 + (t * 2 + s) * 64 + lane];

  f32x4 acc1[4];
  #pragma unroll
  for (int t = 0; t < 4; ++t) {
    #pragma unroll
    for (int r = 0; r < 4; ++r) acc1[t][r] = bc1[t * 16 + g * 4 + r];
  }

  __syncthreads();

  const int v = wv * 16 + vl;
  #pragma unroll
  for (int s = 0; s < 4; ++s) {
    uint4 xb = *(const uint4*)&xt[v][s * 16 + g * 4];
    #pragma unroll
    for (int t = 0; t < 4; ++t) acc1[t] = mfma16(w1f[t][s], xb, acc1[t]);
  }

  #pragma unroll
  for (int t = 0; t < 4; ++t) {
    uint2 pr;
    pr.x = pack_h2(siluf(acc1[t][0]), siluf(acc1[t][1]));
    pr.y = pack_h2(siluf(acc1[t][2]), siluf(acc1[t][3]));
    *(uint2*)&g1b[wv][vl][t * 8 + g * 2] = pr;
  }
  asm volatile("s_waitcnt lgkmcnt(0)" ::: "memory");

  f32x4 acc2[4];
  #pragma unroll
  for (int t = 0; t < 4; ++t) {
    #pragma unroll
    for (int r = 0; r < 4; ++r) acc2[t][r] = bc2[t * 16 + g * 4 + r];
  }
  #pragma unroll
  for (int s = 0; s < 2; ++s) {
    uint4 gv = *(const uint4*)&g1b[wv][vl][s * 16 + g * 4];
    #pragma unroll
    for (int t = 0; t < 4; ++t) acc2[t] = mfma16(w2f[t][s], gv, acc2[t]);
  }

  // residual from staged fp16 grid + store fp16 + per-block stats
  const int dhw = dhw0 + v;
  #pragma unroll
  for (int t = 0; t < 4; ++t) {
    uint2 gp = *(const uint2*)&xt[v][t * 8 + g * 2];
    h2 g0 = as_h2(gp.x), g1 = as_h2(gp.y);
    float gc[4] = {(float)g0.x, (float)g0.y, (float)g1.x, (float)g1.y};
    #pragma unroll
    for (int r = 0; r < 4; ++r) {
      int o = t * 16 + g * 4 + r;
      float grv = gc[r] + acc2[t][r];
      grh[(size_t)(b * 64 + o) * DHW + dhw] = (_Float16)grv;
      float sv = grv, qv = grv * grv;
      sv += __shfl_xor(sv, 1, 64); qv += __shfl_xor(qv, 1, 64);
      sv += __shfl_xor(sv, 2, 64); qv += __shfl_xor(qv, 2, 64);
      sv += __shfl_xor(sv, 4, 64); qv += __shfl_xor(qv, 4, 64);
      sv += __shfl_xor(sv, 8, 64); qv += __shfl_xor(qv, 8, 64);
      if (vl == 0) { part_s[wv][2 * o] = sv; part_s[wv][2 * o + 1] = qv; }
    }
  }
  __syncthreads();
  if (tid < 128)
    partials[(size_t)blockIdx.x * 128 + tid] =
        part_s[0][tid] + part_s[1][tid] + part_s[2][tid] + part_s[3][tid];
}

// ---------------- reduce partials -> per (b,c) scale/shift ----------------
__global__ void stats_kernel(const float* __restrict__ partials, const float* __restrict__ in_g,
                             const float* __restrict__ in_b, float* __restrict__ stats)
{
  int bo = blockIdx.x;
  int b = bo >> 6, o = bo & 63;
  float s = 0.f, q = 0.f;
  for (int k = threadIdx.x; k < 4096; k += 256) {
    const float* pp = partials + (size_t)(b * 4096 + k) * 128 + 2 * o;
    s += pp[0]; q += pp[1];
  }
  __shared__ float sred[256], qred[256];
  sred[threadIdx.x] = s; qred[threadIdx.x] = q;
  __syncthreads();
  for (int st = 128; st >= 1; st >>= 1) {
    if (threadIdx.x < st) { sred[threadIdx.x] += sred[threadIdx.x + st]; qred[threadIdx.x] += qred[threadIdx.x + st]; }
    __syncthreads();
  }
  if (threadIdx.x == 0) {
    float mu = sred[0] * (1.f / (float)DHW);
    float var = qred[0] * (1.f / (float)DHW) - mu * mu;
    float rstd = rsqrtf(var + 1e-5f);
    float scale = rstd * in_g[o];
    stats[2 * bo] = scale;
    stats[2 * bo + 1] = in_b[o] - mu * scale;
  }
}

// ---------------- apply instance norm: grh (fp16) -> gr_out (f32), vectorized ----------------
__global__ void norm_kernel(const uint2* __restrict__ grh2, const float* __restrict__ stats,
                            float* __restrict__ gr)
{
  const size_t total = (size_t)NBATCH * 64 * DHW / 4;   // uint2 count (4 fp16 each)
  size_t stride = (size_t)gridDim.x * 256;
  for (size_t i = blockIdx.x * 256 + threadIdx.x; i < total; i += stride) {
    int bo = (int)(i >> 16);                             // 65536 uint2 per (b,o)
    float scale = stats[2 * bo], shift = stats[2 * bo + 1];
    uint2 u = grh2[i];
    h2 p0 = as_h2(u.x), p1 = as_h2(u.y);
    float4 o;
    o.x = fmaf((float)p0.x, scale, shift);
    o.y = fmaf((float)p0.y, scale, shift);
    o.z = fmaf((float)p1.x, scale, shift);
    o.w = fmaf((float)p1.y, scale, shift);
    *(float4*)&gr[4 * i] = o;
  }
}

extern "C" void kernel_launch(void* const* d_in, const int* in_sizes, int n_in,
                              void* d_out, int out_size, void* d_ws, size_t ws_size,
                              hipStream_t stream)
{
  const float* h     = (const float*)d_in[0];
  const float* x     = (const float*)d_in[1];
  const float* grid  = (const float*)d_in[2];
  const int*   nbat  = (const int*)d_in[3];
  const float* cmin  = (const float*)d_in[4];
  const float* sstr  = (const float*)d_in[5];
  const float* w1    = (const float*)d_in[6];
  const float* b1    = (const float*)d_in[7];
  const float* w2    = (const float*)d_in[8];
  const float* b2    = (const float*)d_in[9];
  const float* ln_g  = (const float*)d_in[10];
  const float* ln_b  = (const float*)d_in[11];
  const float* wn2g  = (const float*)d_in[12];
  const float* bn2g  = (const float*)d_in[13];
  const float* wc1   = (const float*)d_in[14];
  const float* bc1   = (const float*)d_in[15];
  const float* wc2   = (const float*)d_in[16];
  const float* bc2   = (const float*)d_in[17];
  const float* in_g  = (const float*)d_in[18];
  const float* in_b  = (const float*)d_in[19];

  float* hn_out = (float*)d_out;
  float* gr_out = (float*)d_out + (size_t)NNODES * NCH;

  char* ws = (char*)d_ws;
  uint32_t* volh     = (uint32_t*)(ws + VOLH_OFF);     // 134MB fp16 pairs
  float*    partials = (float*)(ws + PART_OFF);
  float*    stats    = (float*)(ws + STAT_OFF);
  uint32_t* nwf      = (uint32_t*)(ws + NWF_OFF);
  uint32_t* wf       = (uint32_t*)(ws + WF_OFF);
  uint32_t* gridT    = (uint32_t*)(ws + GT_OFF);       // 134MB
  _Float16* grh      = (_Float16*)(ws + GRH_OFF);      // 134MB

  pack_all<<<120, 256, 0, stream>>>(w1, w2, wn2g, wc1, wc2, nwf, wf);
  transpose_kernel<<<16384, 256, 0, stream>>>(grid, gridT, (uint4*)volh);
  node_fused<<<3125, 512, 0, stream>>>(h, x, gridT, nbat, cmin, sstr, nwf,
                                       b1, b2, ln_g, ln_b, bn2g, hn_out, volh);
  voxel_kernel<<<16384, 256, 0, stream>>>(gridT, volh, wf, bc1, bc2, grh, partials);
  stats_kernel<<<256, 256, 0, stream>>>(partials, in_g, in_b, stats);
  norm_kernel<<<8192, 256, 0, stream>>>((const uint2*)grh, stats, gr_out);
}